// Round 4
// baseline (887.809 us; speedup 1.0000x reference)
//
#include <hip/hip_runtime.h>

#define NB 256
#define NT 1024
#define NC 128
#define ND 64

typedef _Float16 f16x2_t __attribute__((ext_vector_type(2)));

__device__ __forceinline__ float fexp2(float x){
#if __has_builtin(__builtin_amdgcn_exp2f)
  return __builtin_amdgcn_exp2f(x);
#else
  return exp2f(x);
#endif
}
__device__ __forceinline__ float frcp_(float x){
#if __has_builtin(__builtin_amdgcn_rcpf)
  return __builtin_amdgcn_rcpf(x);
#else
  return 1.0f / x;
#endif
}
__device__ __forceinline__ float sigmoid_f(float x){
  return frcp_(1.0f + fexp2(-1.4426950408889634f * x));
}
__device__ __forceinline__ float tanh_f(float x){
  return 1.0f - 2.0f * frcp_(fexp2(2.8853900817779268f * x) + 1.0f);
}
// exp(CLAMP*0.636*atan(s/CLAMP)) with CLAMP=5 -> exp(3.18*atan(0.2*s))
__device__ __forceinline__ float e_func(float s){
  float u = 0.2f * s;
  float au = fabsf(u);
  bool inv = au > 1.0f;
  float v = inv ? frcp_(au) : au;
  float v2 = v * v;
  float pp = -0.0117212f;
  pp = pp * v2 + 0.05265332f;
  pp = pp * v2 - 0.11643287f;
  pp = pp * v2 + 0.19354346f;
  pp = pp * v2 - 0.33262347f;
  pp = pp * v2 + 0.99997726f;
  float at = pp * v;
  if (inv) at = 1.5707963267948966f - at;
  at = __builtin_copysignf(at, u);
  return fexp2(4.5877702301963f * at); // 3.18 * log2(e) * atan
}

__device__ __forceinline__ unsigned packh(float a, float b){
  union { _Float16 h[2]; unsigned u; } v;
  v.h[0] = (_Float16)a; v.h[1] = (_Float16)b;
  return v.u;
}
__device__ __forceinline__ float fdot2u(unsigned a, unsigned b, float c){
#if __has_builtin(__builtin_amdgcn_fdot2)
  return __builtin_amdgcn_fdot2(__builtin_bit_cast(f16x2_t, a), __builtin_bit_cast(f16x2_t, b), c, false);
#else
  f16x2_t av = __builtin_bit_cast(f16x2_t, a);
  f16x2_t bv = __builtin_bit_cast(f16x2_t, b);
  return c + (float)av[0]*(float)bv[0] + (float)av[1]*(float)bv[1];
#endif
}
__device__ __forceinline__ void load16(unsigned* d, const unsigned* s){
  uint4 a = reinterpret_cast<const uint4*>(s)[0];
  uint4 b = reinterpret_cast<const uint4*>(s)[1];
  uint4 c = reinterpret_cast<const uint4*>(s)[2];
  uint4 e = reinterpret_cast<const uint4*>(s)[3];
  d[0]=a.x; d[1]=a.y; d[2]=a.z; d[3]=a.w;
  d[4]=b.x; d[5]=b.y; d[6]=b.z; d[7]=b.w;
  d[8]=c.x; d[9]=c.y; d[10]=c.z; d[11]=c.w;
  d[12]=e.x; d[13]=e.y; d[14]=e.z; d[15]=e.w;
}

#define DOT16(acc, V, W) do { _Pragma("unroll") for (int kk=0; kk<16; ++kk) acc = fdot2u((V)[kk], (W)[kk], acc); } while(0)

// LDS-only barrier: orders LDS (lgkmcnt) but does NOT drain vmcnt, so global
// y-stores and x-prefetch loads fly across barriers. sched_barrier(0) pins
// ordering around the inline asm (rule #18).
__device__ __forceinline__ void barrier_lds(){
  __builtin_amdgcn_sched_barrier(0);
  asm volatile("s_waitcnt lgkmcnt(0)" ::: "memory");
  __builtin_amdgcn_s_barrier();
  __builtin_amdgcn_sched_barrier(0);
}

// Partials plane layout (conflict-free): p[half][unit]
//   unit in [0,384)    : GRU2 gates. <192 -> gh2 ; >=192 -> gx2 (col-192)
//   unit in [384,768)  : GRU1 gates (same split)
//   unit in [768,896)  : Wo2
//   unit in [896,1024) : Wo1
__global__ __launch_bounds__(512, 1)
void glow_gru_kernel(const float* __restrict__ x,
                     const float* __restrict__ Wx1, const float* __restrict__ Wh1,
                     const float* __restrict__ bx1, const float* __restrict__ bh1,
                     const float* __restrict__ Wo1, const float* __restrict__ bo1,
                     const float* __restrict__ Wx2, const float* __restrict__ Wh2,
                     const float* __restrict__ bx2, const float* __restrict__ bh2,
                     const float* __restrict__ Wo2, const float* __restrict__ bo2,
                     float* __restrict__ out)
{
  __shared__ float p[2][1024];
  __shared__ __align__(16) unsigned h2p[32], h1p[32], y1p[32], x2p[32];
  __shared__ float xf[8][NC];

  const int l = threadIdx.x;      // 0..511
  const int g = l >> 8;           // 0: GRU2-side dots, 1: GRU1-side dots
  const int w2 = (l >> 6) & 3;    // wave within group
  const int half = w2 >> 1;       // k-half (0: k<32, 1: k>=32)
  const int role = w2 & 1;        // 0: {WH r,z,n + WO s} ; 1: {WO t + WX r,z,n}
  const int i = l & 63;
  const int wv = l >> 6;          // global wave id (alpha roles)
  const int b = blockIdx.x;

  // ---- weights into registers: 4 slots x 16 f16-pair dwords = 64 VGPR ----
  const float* WH = g ? Wh1 : Wh2;
  const float* WX = g ? Wx1 : Wx2;
  const float* WO = g ? Wo1 : Wo2;
  unsigned ws[4][16];
  #pragma unroll
  for (int k2 = 0; k2 < 16; ++k2){
    const int k = half*32 + 2*k2;
    if (role == 0){
      ws[0][k2] = packh(WH[k*192 + i],       WH[(k+1)*192 + i]);
      ws[1][k2] = packh(WH[k*192 + 64 + i],  WH[(k+1)*192 + 64 + i]);
      ws[2][k2] = packh(WH[k*192 + 128 + i], WH[(k+1)*192 + 128 + i]);
      ws[3][k2] = packh(WO[k*128 + i],       WO[(k+1)*128 + i]);
    } else {
      ws[0][k2] = packh(WO[k*128 + 64 + i],  WO[(k+1)*128 + 64 + i]);
      ws[1][k2] = packh(WX[k*192 + i],       WX[(k+1)*192 + i]);
      ws[2][k2] = packh(WX[k*192 + 64 + i],  WX[(k+1)*192 + 64 + i]);
      ws[3][k2] = packh(WX[k*192 + 128 + i], WX[(k+1)*192 + 128 + i]);
    }
  }

  // ---- per-lane biases for alpha roles (waves 0..3 only) ----
  float bR = 0.f, bZ = 0.f, bNX = 0.f, bNH = 0.f;
  if (wv == 0){ bR = bx2[i]+bh2[i]; bZ = bx2[64+i]+bh2[64+i]; bNX = bx2[128+i]; bNH = bh2[128+i]; }
  else if (wv == 1){ bR = bo2[i]; bZ = bo2[64+i]; }
  else if (wv == 2){ bR = bx1[i]+bh1[i]; bZ = bx1[64+i]+bh1[64+i]; bNX = bx1[128+i]; bNH = bh1[128+i]; }
  else if (wv == 3){ bR = bo1[i]; bZ = bo1[64+i]; }

  float hreg = 0.f;  // h2 (wave0) / h1 (wave2)

  if (l < 32){ h2p[l] = 0u; h1p[l] = 0u; y1p[l] = 0u; x2p[l] = 0u; }

  // x prefetch owned by waves 4-5 (alpha-idle)
  const long xbase = (long)b * NT * NC;
  const int xl = l - 256;         // valid for waves 4,5: 0..127
  float xr0 = 0.f, xr1 = 0.f;
  if (xl >= 0 && xl < 128){ xr0 = x[xbase + xl]; xr1 = x[xbase + NC + xl]; }
  __syncthreads();

  for (int j = -1; j <= NT + 2; ++j){
    // ================= Phase alpha =================
    if (wv == 0){
      // act2(j) -> h2n
      if (j >= 0 && j < NT){
        __builtin_amdgcn_s_setprio(1);
        float rh = p[0][i]     + p[1][i];
        float zh = p[0][64+i]  + p[1][64+i];
        float nh = p[0][128+i] + p[1][128+i];
        float rx = p[0][192+i] + p[1][192+i];
        float zx = p[0][256+i] + p[1][256+i];
        float nx = p[0][320+i] + p[1][320+i];
        float r = sigmoid_f(rx + rh + bR);
        float z = sigmoid_f(zx + zh + bZ);
        float n = tanh_f(nx + bNX + r*(nh + bNH));
        hreg = (1.0f - z)*n + z*hreg;
        reinterpret_cast<_Float16*>(h2p)[i] = (_Float16)hreg;
        __builtin_amdgcn_s_setprio(0);
      }
    } else if (wv == 1){
      // y1(j-1)
      const int t = j - 1;
      if (t >= 0 && t < NT){
        __builtin_amdgcn_s_setprio(1);
        float s2v = p[0][768+i] + p[1][768+i] + bR;
        float t2  = p[0][832+i] + p[1][832+i] + bZ;
        float y1 = e_func(s2v) * xf[t & 7][i] + t2;
        reinterpret_cast<_Float16*>(y1p)[i] = (_Float16)y1;
        __builtin_amdgcn_s_setprio(0);
        out[xbase + (long)t*NC + i] = y1;
      }
    } else if (wv == 2){
      // act1(j-2) -> h1n
      const int t = j - 2;
      if (t >= 0 && t < NT){
        __builtin_amdgcn_s_setprio(1);
        float rh = p[0][384+i] + p[1][384+i];
        float zh = p[0][448+i] + p[1][448+i];
        float nh = p[0][512+i] + p[1][512+i];
        float rx = p[0][576+i] + p[1][576+i];
        float zx = p[0][640+i] + p[1][640+i];
        float nx = p[0][704+i] + p[1][704+i];
        float r = sigmoid_f(rx + rh + bR);
        float z = sigmoid_f(zx + zh + bZ);
        float n = tanh_f(nx + bNX + r*(nh + bNH));
        hreg = (1.0f - z)*n + z*hreg;
        reinterpret_cast<_Float16*>(h1p)[i] = (_Float16)hreg;
        __builtin_amdgcn_s_setprio(0);
      }
    } else if (wv == 3){
      // y2(j-3)
      const int t = j - 3;
      if (t >= 0 && t < NT){
        __builtin_amdgcn_s_setprio(1);
        float s1v = p[0][896+i] + p[1][896+i] + bR;
        float t1  = p[0][960+i] + p[1][960+i] + bZ;
        float y2 = e_func(s1v) * xf[t & 7][64+i] + t1;
        __builtin_amdgcn_s_setprio(0);
        out[xbase + (long)t*NC + 64 + i] = y2;
      }
    } else if (xl >= 0 && xl < 128){
      // waves 4-5: stage x(j+1) and advance 2-deep prefetch
      if ((j + 1) < NT){
        xf[(j+1) & 7][xl] = xr0;
        if (xl >= 64) reinterpret_cast<_Float16*>(x2p)[xl-64] = (_Float16)xr0;
      }
      xr0 = xr1;
      if ((j + 3) < NT) xr1 = x[xbase + (long)(j+3)*NC + xl];
    }
    barrier_lds();
    if (j == NT + 2) break;

    // ================= Phase beta: 8 half-matvecs, wave-uniform operands ====
    {
      const int pb = g * 384;
      const int ob = 768 + g * 128;
      unsigned hv[16];
      load16(hv, (g ? h1p : h2p) + half*16);
      if (role == 0){
        float a0=0.f, a1=0.f, a2=0.f, a3=0.f;
        DOT16(a0, hv, ws[0]);
        DOT16(a1, hv, ws[1]);
        DOT16(a2, hv, ws[2]);
        DOT16(a3, hv, ws[3]);
        p[half][pb+i]      = a0;
        p[half][pb+64+i]   = a1;
        p[half][pb+128+i]  = a2;
        p[half][ob+i]      = a3;
      } else {
        unsigned ov[16];
        load16(ov, (g ? y1p : x2p) + half*16);
        float a0=0.f, a1=0.f, a2=0.f, a3=0.f;
        DOT16(a0, hv, ws[0]);
        DOT16(a1, ov, ws[1]);
        DOT16(a2, ov, ws[2]);
        DOT16(a3, ov, ws[3]);
        p[half][ob+64+i]   = a0;
        p[half][pb+192+i]  = a1;
        p[half][pb+256+i]  = a2;
        p[half][pb+320+i]  = a3;
      }
    }
    barrier_lds();
  }
}

extern "C" void kernel_launch(void* const* d_in, const int* in_sizes, int n_in,
                              void* d_out, int out_size, void* d_ws, size_t ws_size,
                              hipStream_t stream) {
  const float* x   = (const float*)d_in[0];
  const float* Wx1 = (const float*)d_in[1];
  const float* Wh1 = (const float*)d_in[2];
  const float* bx1 = (const float*)d_in[3];
  const float* bh1 = (const float*)d_in[4];
  const float* Wo1 = (const float*)d_in[5];
  const float* bo1 = (const float*)d_in[6];
  const float* Wx2 = (const float*)d_in[7];
  const float* Wh2 = (const float*)d_in[8];
  const float* bx2 = (const float*)d_in[9];
  const float* bh2 = (const float*)d_in[10];
  const float* Wo2 = (const float*)d_in[11];
  const float* bo2 = (const float*)d_in[12];
  float* out = (float*)d_out;

  hipLaunchKernelGGL(glow_gru_kernel, dim3(NB), dim3(512), 0, stream,
                     x, Wx1, Wh1, bx1, bh1, Wo1, bo1,
                     Wx2, Wh2, bx2, bh2, Wo2, bo2, out);
}